// Round 1
// baseline (93.660 us; speedup 1.0000x reference)
//
#include <hip/hip_runtime.h>
#include <math.h>

// ---------------------------------------------------------------------------
// ReductionAndExpansionAreaResamp: area-resample [B,L_IN,D] -> [B,maxT,D]
// with exact integer-bin averaging + fractional-overlap std noise.
// Outputs (concatenated in d_out): out [B,maxT,D] f32, out_mask [B,maxT] (0/1).
// Noise RNG: JAX threefry2x32 PARTITIONABLE path (verified round 2):
//   per element n: (x0,x1)=threefry2x32(key=(0,42), counts=(0,n)); bits=x0^x1.
//
// R8 structure (single kernel, latency-oriented rewrite of R7):
//   - L[b] found by a 2-round 64-ary ballot search on the monotone suffix
//     mask (2 dependent load rounds instead of 12 serial binary-search loads).
//   - Window rows (hi-lo <= 6 for this problem: step = L/T <= 4) prefetched
//     into registers with clamped indices BEFORE the threefry/erfinv block,
//     so all loads are in flight under ~500 cycles of RNG VALU work.
//     Accumulation order is bit-identical to R7 (k<n predication; k>=n terms
//     are exactly zero and skipped). Rare n>6 falls back to the R7 loop.
//   - XCD-aware swizzle of blockIdx.x (nbx % 8 == 0 -> bijective) so each
//     XCD reads a contiguous ~4MB slice of x (L2-resident).
//   One WAVE per (b,t); lane owns 4 consecutive d (float4). No LDS/barriers.
// ---------------------------------------------------------------------------

__device__ __forceinline__ unsigned rotl32(unsigned x, unsigned r) {
  return (x << r) | (x >> (32u - r));
}

// JAX threefry2x32 (20 rounds), key injection schedule per jax/_src/prng.py
__device__ __forceinline__ void threefry2x32(unsigned ks0, unsigned ks1,
                                             unsigned& x0, unsigned& x1) {
  const unsigned ks2 = ks0 ^ ks1 ^ 0x1BD11BDAu;
  x0 += ks0; x1 += ks1;
#define TFR(r) { x0 += x1; x1 = rotl32(x1, (r)); x1 ^= x0; }
  TFR(13u) TFR(15u) TFR(26u) TFR(6u)   x0 += ks1; x1 += ks2 + 1u;
  TFR(17u) TFR(29u) TFR(16u) TFR(24u)  x0 += ks2; x1 += ks0 + 2u;
  TFR(13u) TFR(15u) TFR(26u) TFR(6u)   x0 += ks0; x1 += ks1 + 3u;
  TFR(17u) TFR(29u) TFR(16u) TFR(24u)  x0 += ks1; x1 += ks2 + 4u;
  TFR(13u) TFR(15u) TFR(26u) TFR(6u)   x0 += ks2; x1 += ks0 + 5u;
#undef TFR
}

// One wave per (b,t). Lane owns d = 4*lane .. 4*lane+3 (requires D == 256).
__global__ __launch_bounds__(256) void resample_kernel(
    const float* __restrict__ x, const int* __restrict__ finallength,
    const int* __restrict__ padding_mask, float* __restrict__ out,
    float* __restrict__ out_mask, int L_in) {
  const int D = 256;
  const int wave = threadIdx.x >> 6;
  const int lane = threadIdx.x & 63;
  const int maxT = gridDim.x * 4;

  // --- XCD-aware swizzle: consecutive-linear blocks land on different XCDs;
  // remap so each XCD owns a contiguous t-chunk (L2 locality on x rows).
  int bx = blockIdx.x;
  const int nbx = gridDim.x;
  if ((nbx & 7) == 0) {
    const int q = nbx >> 3;
    bx = (bx & 7) * q + (bx >> 3);      // bijective (nbx % 8 == 0)
  }
  const int t = bx * 4 + wave;
  const int b = blockIdx.y;
  const int bt = b * maxT + t;
  const size_t obase = (size_t)bt * D + lane * 4;   // flat elem idx of .x

  // --- L[b] via 2-round 64-ary ballot search on the monotone suffix mask ---
  const int* __restrict__ m = padding_mask + (size_t)b * L_in;
  const int T = finallength[b];                      // issues alongside probe

  const int stride = (L_in + 63) >> 6;               // 64 for L_in = 4096
  int p1 = (lane + 1) * stride - 1;                  // last element of chunk
  if (p1 >= L_in) p1 = L_in - 1;
  const unsigned long long m1 = __ballot(m[p1] != 0);
  int L = L_in;
  if (m1 != 0ull) {
    const int c = (int)__ffsll(m1) - 1;              // first chunk w/ a pad
    const int base = c * stride;
    const int cend = (base + stride < L_in) ? base + stride : L_in;
    for (int off = 0; ; off += 64) {
      const int p2 = base + off + lane;
      const bool in = p2 < cend;
      const int pc = (p2 < L_in) ? p2 : (L_in - 1);
      const unsigned long long m2 = __ballot(in && (m[pc] != 0));
      if (m2 != 0ull) { L = base + off + (int)__ffsll(m2) - 1; break; }
      if (base + off + 64 >= cend) break;            // unreachable in practice
    }
  }

  if (t >= T || L <= 0) {                            // invalid bin: zeros+mask
    *(float4*)(out + obase) = make_float4(0.f, 0.f, 0.f, 0.f);
    if (lane == 0) out_mask[bt] = 1.0f;
    return;                                          // skip RNG entirely
  }

  // --- wave-uniform bin parameters (u32; t*L < 2^31) -----------------------
  const unsigned Tc = (unsigned)T;                   // T >= 1 here
  const unsigned jL = (unsigned)t * (unsigned)L;
  const int i0 = (int)(jL / Tc);
  const int i1 = (int)((jL + (unsigned)L + Tc - 1u) / Tc);
  const float step = (float)L / (float)Tc;           // exact f32 replication
  const float start = (float)t * step;
  const float end = start + step;
  int flo = (int)floorf(start); if (flo < 0) flo = 0;
  int fhi = (int)ceilf(end);    if (fhi > L) fhi = L;
  const int lo = (i0 < flo) ? i0 : flo;              // i1 <= L, fhi <= L =>
  const int hi = (i1 > fhi) ? i1 : fhi;              // hi <= L, no (i>=L) case
  const int n = hi - lo;                             // >= 1; <= 6 for step<=4

  // --- prefetch window rows into registers (clamped idx; loads in flight) --
  // Suffix mask => compacted row i is original row i; direct float4 loads.
  const float4* __restrict__ xr =
      (const float4*)(x + (size_t)b * L_in * D) + lane;   // + i*64 per row
  constexpr int PREF = 6;
  float4 v0, v1, v2, v3, v4, v5;
  {
    const int k0 = lo;
    const int k1 = lo + ((1 < n) ? 1 : 0);
    const int k2 = lo + ((2 < n) ? 2 : 0);
    const int k3 = lo + ((3 < n) ? 3 : 0);
    const int k4 = lo + ((4 < n) ? 4 : 0);
    const int k5 = lo + ((5 < n) ? 5 : 0);
    v0 = xr[(size_t)k0 * 64];
    v1 = xr[(size_t)k1 * 64];
    v2 = xr[(size_t)k2 * 64];
    v3 = xr[(size_t)k3 * 64];
    v4 = xr[(size_t)k4 * 64];
    v5 = xr[(size_t)k5 * 64];
  }

  // --- eps_noise for 4 elements: partitionable threefry --------------------
  // (pure VALU; hides the prefetch latency above)
  float z[4];
#pragma unroll
  for (int k = 0; k < 4; ++k) {
    unsigned c0 = 0u, c1 = (unsigned)obase + (unsigned)k;
    threefry2x32(0u, 42u, c0, c1);
    const unsigned bits = c0 ^ c1;
    union { unsigned u; float f; } cvt;
    cvt.u = (bits >> 9) | 0x3F800000u;
    const float lof = -0.99999994f;                  // nextafter(-1,0) in f32
    float uu = (cvt.f - 1.0f) * 2.0f + lof;
    uu = fmaxf(lof, uu);
    z[k] = 1.41421356237309515f * erfinvf(uu);
  }

  // --- fused integer-bin average + fractional-window moments ---------------
  float4 sI = make_float4(0.f, 0.f, 0.f, 0.f);
  float4 sX = make_float4(0.f, 0.f, 0.f, 0.f);
  float4 sXX = make_float4(0.f, 0.f, 0.f, 0.f);
  float sW = 0.f;

#define ACC_ROW(K, V)                                                        \
  if ((K) < n) {                                                             \
    const int i = lo + (K);                                                  \
    const float4 vv = (V);                                                   \
    if (i >= i0 && i < i1) {                                                 \
      sI.x += vv.x; sI.y += vv.y; sI.z += vv.z; sI.w += vv.w;                \
    }                                                                        \
    float w = fminf((float)(i + 1), end) - fmaxf((float)i, start);           \
    w = fmaxf(w, 0.f);                                                       \
    sW += w;                                                                 \
    sX.x += w * vv.x; sX.y += w * vv.y; sX.z += w * vv.z; sX.w += w * vv.w;  \
    sXX.x += w * vv.x * vv.x; sXX.y += w * vv.y * vv.y;                      \
    sXX.z += w * vv.z * vv.z; sXX.w += w * vv.w * vv.w;                      \
  }
  ACC_ROW(0, v0)
  ACC_ROW(1, v1)
  ACC_ROW(2, v2)
  ACC_ROW(3, v3)
  ACC_ROW(4, v4)
  ACC_ROW(5, v5)
#undef ACC_ROW

  // Cold fallback (n > 6 cannot happen for this problem's T >= maxT/2, but
  // keep the kernel generic). Same body, same accumulation order.
  for (int i = lo + PREF; i < hi; ++i) {
    const float4 vv = xr[(size_t)i * 64];
    if (i >= i0 && i < i1) {
      sI.x += vv.x; sI.y += vv.y; sI.z += vv.z; sI.w += vv.w;
    }
    float w = fminf((float)(i + 1), end) - fmaxf((float)i, start);
    w = fmaxf(w, 0.f);
    sW += w;
    sX.x += w * vv.x; sX.y += w * vv.y; sX.z += w * vv.z; sX.w += w * vv.w;
    sXX.x += w * vv.x * vv.x; sXX.y += w * vv.y * vv.y;
    sXX.z += w * vv.z * vv.z; sXX.w += w * vv.w * vv.w;
  }

  const int cd = i1 - i0;
  const float inv_cnt = 1.f / (float)((cd > 1) ? cd : 1);
  const float inv_ws = 1.f / fmaxf(sW, 1e-12f);
  float4 o;
  {
    const float mean = sX.x * inv_ws, msq = sXX.x * inv_ws;
    o.x = sI.x * inv_cnt + (z[0] * sqrtf(fmaxf(msq - mean * mean, 1e-12f))) * 0.1f;
  }
  {
    const float mean = sX.y * inv_ws, msq = sXX.y * inv_ws;
    o.y = sI.y * inv_cnt + (z[1] * sqrtf(fmaxf(msq - mean * mean, 1e-12f))) * 0.1f;
  }
  {
    const float mean = sX.z * inv_ws, msq = sXX.z * inv_ws;
    o.z = sI.z * inv_cnt + (z[2] * sqrtf(fmaxf(msq - mean * mean, 1e-12f))) * 0.1f;
  }
  {
    const float mean = sX.w * inv_ws, msq = sXX.w * inv_ws;
    o.w = sI.w * inv_cnt + (z[3] * sqrtf(fmaxf(msq - mean * mean, 1e-12f))) * 0.1f;
  }
  *(float4*)(out + obase) = o;
  if (lane == 0) out_mask[bt] = 0.0f;
}

extern "C" void kernel_launch(void* const* d_in, const int* in_sizes, int n_in,
                              void* d_out, int out_size, void* d_ws, size_t ws_size,
                              hipStream_t stream) {
  const float* x            = (const float*)d_in[0];
  const int*   finallength  = (const int*)d_in[1];
  const int*   padding_mask = (const int*)d_in[2];

  const int B    = in_sizes[1];                  // 8
  const int L_in = in_sizes[2] / B;              // 4096
  const int D    = in_sizes[0] / in_sizes[2];    // 256 (resample assumes 256)
  const int maxT = out_size / (B * (D + 1));     // 2048

  float* out      = (float*)d_out;
  float* out_mask = out + (size_t)B * maxT * D;
  (void)d_ws; (void)ws_size; (void)n_in; (void)D;

  resample_kernel<<<dim3(maxT / 4, B), 256, 0, stream>>>(
      x, finallength, padding_mask, out, out_mask, L_in);
}